// Round 1
// baseline (7907.011 us; speedup 1.0000x reference)
//
#include <hip/hip_runtime.h>

typedef short s16x8 __attribute__((ext_vector_type(8)));
typedef float f32x4 __attribute__((ext_vector_type(4)));
typedef unsigned int u32;
typedef unsigned short u16;
typedef u32 u32x4 __attribute__((ext_vector_type(4)));
typedef u16 u16x4 __attribute__((ext_vector_type(4)));

#define DEVI static __device__ __forceinline__

constexpr int HORIZON = 30;
constexpr int BATCH = 65536;
constexpr int INDIM = 384;
constexpr int DEC = 256;
constexpr int G3 = 768;
constexpr int BM = 256;          // batch rows per block
constexpr int NTHR = 512;        // 8 waves
constexpr int NW = 8;
constexpr int GRIDN = BATCH / BM;  // 256 blocks = 1 per CU (persistent)
constexpr long MU_N = (long)BATCH * HORIZON * 2;   // offset of cov in out

// LDS layout (bytes)
constexpr int H_STRIDE = 528;                    // 256 bf16 cols + 8 pad cols
constexpr int ST_STRIDE = 784;                   // staging: 384 bf16 cols + pad
constexpr int LDS_GT   = 256 * H_STRIDE;         // 135168: gatetab [768][4] f32 {wx,wy,bhh,bih}
constexpr int LDS_WOUT = LDS_GT + G3 * 16;       // 147456: wout [5][256] f32
constexpr int LDS_BH0  = LDS_WOUT + 5 * 256 * 4; // 152576: b_hinit [256] f32
constexpr int LDS_MU   = LDS_BH0 + 256 * 4;      // 153600: mu [256][2] f32
constexpr int LDS_BOUT = LDS_MU + 256 * 2 * 4;   // 155648: bout [8] f32
constexpr int LDS_TOTAL = LDS_BOUT + 32;         // 155680 <= 163840

// workspace layout (bytes)
constexpr size_t WS_WHH    = 0;                       // [768][256] bf16 = 393216
constexpr size_t WS_WIHA   = 393216;                  // [768][384] bf16 = 589824
constexpr size_t WS_WHINIT = 983040;                  // [256][384] bf16 = 196608
constexpr size_t WS_GI     = 1179648;                 // [256 blk][8 wave][3072 uint4]

DEVI f32x4 mfma(s16x8 a, s16x8 b, f32x4 c) {
  return __builtin_amdgcn_mfma_f32_16x16x32_bf16(a, b, c, 0, 0, 0);
}
DEVI u16 f2b(float f) {
  // round-to-nearest-even f32 -> bf16
  u32 u = __builtin_bit_cast(u32, f);
  u32 r = (u + 0x7fff + ((u >> 16) & 1)) >> 16;
  return (u16)r;
}
DEVI float b2f(u16 s) { return __builtin_bit_cast(float, ((u32)s) << 16); }
DEVI u32 pack2(float lo, float hi) { return (u32)f2b(lo) | ((u32)f2b(hi) << 16); }
DEVI float gilo(u32 u) { return __builtin_bit_cast(float, u << 16); }
DEVI float gihi(u32 u) { return __builtin_bit_cast(float, u & 0xFFFF0000u); }
DEVI float sigm(float x) { return 1.0f / (1.0f + __expf(-x)); }
DEVI float tanh_(float x) { return 1.0f - 2.0f / (__expf(2.0f * x) + 1.0f); }

// ---------------- setup kernels: convert weights to bf16 ----------------
extern "C" __global__ void cvt_whh(const float* __restrict__ in, u16* __restrict__ out) {
  int i = blockIdx.x * 256 + threadIdx.x;           // 768 blocks
  out[i] = f2b(in[i]);                              // [768][256] row-major preserved
}
extern "C" __global__ void cvt_wiha(const float* __restrict__ in, u16* __restrict__ out) {
  int j = blockIdx.x, k = threadIdx.x;              // 768 blocks x 384 thr
  out[j * 384 + k] = f2b(in[j * 386 + k]);          // strip mu columns
}
extern "C" __global__ void cvt_whinit(const float* __restrict__ in, u16* __restrict__ out) {
  int i = blockIdx.x * 256 + threadIdx.x;           // 384 blocks
  out[i] = f2b(in[i]);                              // [256][384]
}

// ---------------- main persistent kernel ----------------
extern "C" __global__ void __launch_bounds__(NTHR, 2)
traj_main(const float* __restrict__ zh, const float* __restrict__ b_hinit,
          const float* __restrict__ W_ih, const float* __restrict__ b_ih,
          const float* __restrict__ b_hh,
          const float* __restrict__ W_mu, const float* __restrict__ b_mu,
          const float* __restrict__ W_cov, const float* __restrict__ b_cov,
          const u16* __restrict__ whh, const u16* __restrict__ wiha,
          const u16* __restrict__ whinit,
          u16* __restrict__ gi_ws, float* __restrict__ out) {
  extern __shared__ char smem[];
  const int tid = threadIdx.x;
  const int lane = tid & 63;
  const int w = tid >> 6;       // wave 0..7
  const int wm = w & 1;         // row half: rows [wm*128, +128)
  const int wn = w >> 1;        // gate-col quarter: cols [wn*64, +64) per gate
  const int q = lane >> 4;
  const int l15 = lane & 15;
  const int blk = blockIdx.x;
  const long rowg0 = (long)blk * BM;

  float* gt = (float*)(smem + LDS_GT);
  float* wout = (float*)(smem + LDS_WOUT);
  float* bh0 = (float*)(smem + LDS_BH0);
  float* mul = (float*)(smem + LDS_MU);
  float* bo = (float*)(smem + LDS_BOUT);

  // ---- misc LDS fill
  for (int j = tid; j < G3; j += NTHR) {
    f32x4 v;
    v.x = W_ih[j * 386 + 384]; v.y = W_ih[j * 386 + 385];
    v.z = b_hh[j];             v.w = b_ih[j];
    *(f32x4*)(gt + j * 4) = v;
  }
  for (int idx = tid; idx < 5 * 256; idx += NTHR) {
    int o = idx >> 8, c = idx & 255;
    wout[idx] = (o < 2) ? W_mu[o * 256 + c] : W_cov[(o - 2) * 256 + c];
  }
  if (tid < 256) bh0[tid] = b_hinit[tid];
  if (tid < 8) bo[tid] = (tid < 2) ? b_mu[tid] : (tid < 5 ? b_cov[tid - 2] : 0.0f);

  // ---- phase A: gi = zh@W_ihA^T + b_ih (to ws, packed), h0 = zh@W_hinit^T + b_hinit
  u32 h0h[64];
  u32x4* gi4w = (u32x4*)(gi_ws) + (size_t)(blk * NW + w) * 3072;

  for (int half = 0; half < 2; ++half) {
    __syncthreads();  // misc done / previous half compute done before restaging
    {  // stage zh rows [half*128, +128) as bf16 into staging region (aliases h)
      const float4* src = (const float4*)(zh + (rowg0 + half * 128) * INDIM);
      #pragma unroll
      for (int i = 0; i < 24; ++i) {
        int f = tid + i * NTHR;                // 0..12287
        int row = f / 96, c4 = f - row * 96;
        float4 v = src[row * 96 + c4];
        u16x4 p; p.x = f2b(v.x); p.y = f2b(v.y); p.z = f2b(v.z); p.w = f2b(v.w);
        *(u16x4*)(smem + row * ST_STRIDE + c4 * 8) = p;
      }
    }
    __syncthreads();
    if (wm == half) {
      // gi chunks: 4 chunks x (3 gates x 16 cols), K=384
      for (int c = 0; c < 4; ++c) {
        f32x4 acc[3][8];
        #pragma unroll
        for (int g = 0; g < 3; ++g)
          #pragma unroll
          for (int m = 0; m < 8; ++m) acc[g][m] = (f32x4)(0.0f);
        #pragma unroll
        for (int kb = 0; kb < 12; ++kb) {
          s16x8 a[8];
          #pragma unroll
          for (int m = 0; m < 8; ++m)
            a[m] = *(const s16x8*)(smem + (m * 16 + l15) * ST_STRIDE + kb * 64 + q * 16);
          #pragma unroll
          for (int g = 0; g < 3; ++g) {
            int cg = g * 256 + wn * 64 + c * 16 + l15;
            s16x8 bb = *(const s16x8*)(wiha + cg * INDIM + kb * 32 + q * 8);
            #pragma unroll
            for (int m = 0; m < 8; ++m) acc[g][m] = mfma(a[m], bb, acc[g][m]);
          }
        }
        u32x4 st[12];
        #pragma unroll
        for (int g = 0; g < 3; ++g) {
          f32x4 tab = *(const f32x4*)(gt + (g * 256 + wn * 64 + c * 16 + l15) * 4);
          #pragma unroll
          for (int m = 0; m < 8; ++m) {
            u32 lo = pack2(acc[g][m][0] + tab.w, acc[g][m][1] + tab.w);
            u32 hi = pack2(acc[g][m][2] + tab.w, acc[g][m][3] + tab.w);
            st[(g * 8 + m) >> 1][(m & 1) * 2] = lo;
            st[(g * 8 + m) >> 1][(m & 1) * 2 + 1] = hi;
          }
        }
        #pragma unroll
        for (int i = 0; i < 12; ++i) gi4w[(c * 12 + i) * 64 + lane] = st[i];
      }
      // h0 chunks: 2 chunks x 32 cols, K=384
      for (int hc = 0; hc < 2; ++hc) {
        f32x4 acc[2][8];
        #pragma unroll
        for (int nt = 0; nt < 2; ++nt)
          #pragma unroll
          for (int m = 0; m < 8; ++m) acc[nt][m] = (f32x4)(0.0f);
        #pragma unroll
        for (int kb = 0; kb < 12; ++kb) {
          s16x8 a[8];
          #pragma unroll
          for (int m = 0; m < 8; ++m)
            a[m] = *(const s16x8*)(smem + (m * 16 + l15) * ST_STRIDE + kb * 64 + q * 16);
          #pragma unroll
          for (int nt = 0; nt < 2; ++nt) {
            int col = wn * 64 + hc * 32 + nt * 16 + l15;
            s16x8 bb = *(const s16x8*)(whinit + col * INDIM + kb * 32 + q * 8);
            #pragma unroll
            for (int m = 0; m < 8; ++m) acc[nt][m] = mfma(a[m], bb, acc[nt][m]);
          }
        }
        #pragma unroll
        for (int nt = 0; nt < 2; ++nt) {
          float bias = bh0[wn * 64 + hc * 32 + nt * 16 + l15];
          #pragma unroll
          for (int m = 0; m < 8; ++m) {
            int o = hc * 32 + (nt * 8 + m) * 2;
            h0h[o] = pack2(acc[nt][m][0] + bias, acc[nt][m][1] + bias);
            h0h[o + 1] = pack2(acc[nt][m][2] + bias, acc[nt][m][3] + bias);
          }
        }
      }
    }
  }
  __syncthreads();  // staging no longer needed -> h region writable
  // write h0 (held in regs) into h_lds
  #pragma unroll
  for (int hc = 0; hc < 2; ++hc)
    #pragma unroll
    for (int nt = 0; nt < 2; ++nt)
      #pragma unroll
      for (int m = 0; m < 8; ++m) {
        int col = wn * 64 + hc * 32 + nt * 16 + l15;
        int o = hc * 32 + (nt * 8 + m) * 2;
        int row0 = wm * 128 + m * 16 + q * 4;
        *(u16*)(smem + (row0 + 0) * H_STRIDE + col * 2) = (u16)(h0h[o] & 0xFFFF);
        *(u16*)(smem + (row0 + 1) * H_STRIDE + col * 2) = (u16)(h0h[o] >> 16);
        *(u16*)(smem + (row0 + 2) * H_STRIDE + col * 2) = (u16)(h0h[o + 1] & 0xFFFF);
        *(u16*)(smem + (row0 + 3) * H_STRIDE + col * 2) = (u16)(h0h[o + 1] >> 16);
      }
  if (tid < 512) mul[tid] = 0.0f;  // mu0 = 0
  __syncthreads();

  const u32x4* gi4 = (const u32x4*)(gi_ws) + (size_t)(blk * NW + w) * 3072;

  // ---- phase B: 30 recurrent steps
  #pragma unroll 1
  for (int t = 0; t < HORIZON; ++t) {
    u32 hh[64];  // held h_next (bf16 pairs), written to LDS after barrier A
    #pragma unroll
    for (int c = 0; c < 4; ++c) {
      u32x4 gv[12];
      #pragma unroll
      for (int i = 0; i < 6; ++i) gv[i] = gi4[(c * 12 + i) * 64 + lane];
      f32x4 acc[3][8];
      #pragma unroll
      for (int g = 0; g < 3; ++g)
        #pragma unroll
        for (int m = 0; m < 8; ++m) acc[g][m] = (f32x4)(0.0f);
      #pragma unroll
      for (int kb = 0; kb < 8; ++kb) {
        if (kb == 4) {
          #pragma unroll
          for (int i = 6; i < 12; ++i) gv[i] = gi4[(c * 12 + i) * 64 + lane];
        }
        s16x8 a[8];
        #pragma unroll
        for (int m = 0; m < 8; ++m)
          a[m] = *(const s16x8*)(smem + (wm * 128 + m * 16 + l15) * H_STRIDE + kb * 64 + q * 16);
        #pragma unroll
        for (int g = 0; g < 3; ++g) {
          s16x8 bb = *(const s16x8*)(whh + (g * 256 + wn * 64 + c * 16 + l15) * DEC + kb * 32 + q * 8);
          #pragma unroll
          for (int m = 0; m < 8; ++m) acc[g][m] = mfma(a[m], bb, acc[g][m]);
        }
      }
      // epilogue: gates -> h_next (held)
      int colh = wn * 64 + c * 16 + l15;
      f32x4 tabR = *(const f32x4*)(gt + (0 * 256 + colh) * 4);
      f32x4 tabZ = *(const f32x4*)(gt + (1 * 256 + colh) * 4);
      f32x4 tabN = *(const f32x4*)(gt + (2 * 256 + colh) * 4);
      #pragma unroll
      for (int m = 0; m < 8; ++m) {
        int row0 = wm * 128 + m * 16 + q * 4;
        f32x4 muA = *(const f32x4*)(mul + row0 * 2);
        f32x4 muB = *(const f32x4*)(mul + row0 * 2 + 4);
        float mux[4] = {muA.x, muA.z, muB.x, muB.z};
        float muy[4] = {muA.y, muA.w, muB.y, muB.w};
        u32 wR0 = gv[(0 * 8 + m) >> 1][(m & 1) * 2], wR1 = gv[(0 * 8 + m) >> 1][(m & 1) * 2 + 1];
        u32 wZ0 = gv[(1 * 8 + m) >> 1][(m & 1) * 2], wZ1 = gv[(1 * 8 + m) >> 1][(m & 1) * 2 + 1];
        u32 wN0 = gv[(2 * 8 + m) >> 1][(m & 1) * 2], wN1 = gv[(2 * 8 + m) >> 1][(m & 1) * 2 + 1];
        float tmp0 = 0.0f;
        #pragma unroll
        for (int r = 0; r < 4; ++r) {
          float giR = (r == 0) ? gilo(wR0) : (r == 1) ? gihi(wR0) : (r == 2) ? gilo(wR1) : gihi(wR1);
          float giZ = (r == 0) ? gilo(wZ0) : (r == 1) ? gihi(wZ0) : (r == 2) ? gilo(wZ1) : gihi(wZ1);
          float giN = (r == 0) ? gilo(wN0) : (r == 1) ? gihi(wN0) : (r == 2) ? gilo(wN1) : gihi(wN1);
          float rin = acc[0][m][r] + tabR.z + giR + mux[r] * tabR.x + muy[r] * tabR.y;
          float zin = acc[1][m][r] + tabZ.z + giZ + mux[r] * tabZ.x + muy[r] * tabZ.y;
          float hn  = acc[2][m][r] + tabN.z;
          float rr = sigm(rin), zz = sigm(zin);
          float nin = giN + mux[r] * tabN.x + muy[r] * tabN.y + rr * hn;
          float nn = tanh_(nin);
          float hp = b2f(*(const u16*)(smem + (row0 + r) * H_STRIDE + colh * 2));
          float hv = nn + zz * (hp - nn);
          if ((r & 1) == 0) tmp0 = hv;
          else hh[c * 16 + m * 2 + (r >> 1)] = pack2(tmp0, hv);
        }
      }
    }
    __syncthreads();  // A: all waves done reading h
    #pragma unroll
    for (int c = 0; c < 4; ++c)
      #pragma unroll
      for (int m = 0; m < 8; ++m)
        #pragma unroll
        for (int p = 0; p < 2; ++p) {
          u32 v = hh[c * 16 + m * 2 + p];
          int row0 = wm * 128 + m * 16 + q * 4 + p * 2;
          int colh = wn * 64 + c * 16 + l15;
          *(u16*)(smem + row0 * H_STRIDE + colh * 2) = (u16)(v & 0xFFFF);
          *(u16*)(smem + (row0 + 1) * H_STRIDE + colh * 2) = (u16)(v >> 16);
        }
    __syncthreads();  // B: h_next visible
    // mu/cov GEMV via MFMA: out5 = h @ [W_mu;W_cov]^T, N padded to 16
    {
      f32x4 acc2[2] = {(f32x4)(0.0f), (f32x4)(0.0f)};
      #pragma unroll
      for (int kb = 0; kb < 8; ++kb) {
        s16x8 bb;
        if (l15 < 5) {
          const float* wp = wout + l15 * 256 + kb * 32 + q * 8;
          #pragma unroll
          for (int j = 0; j < 8; ++j) bb[j] = (short)f2b(wp[j]);
        } else {
          #pragma unroll
          for (int j = 0; j < 8; ++j) bb[j] = 0;
        }
        #pragma unroll
        for (int m = 0; m < 2; ++m) {
          s16x8 a = *(const s16x8*)(smem + (w * 32 + m * 16 + l15) * H_STRIDE + kb * 64 + q * 16);
          acc2[m] = mfma(a, bb, acc2[m]);
        }
      }
      float bias = (l15 < 5) ? bo[l15] : 0.0f;
      #pragma unroll
      for (int m = 0; m < 2; ++m)
        #pragma unroll
        for (int r = 0; r < 4; ++r) {
          int row = w * 32 + m * 16 + q * 4 + r;
          long grow = rowg0 + row;
          float v = acc2[m][r] + bias;
          if (l15 == 0) { out[(grow * HORIZON + t) * 2] = v; mul[row * 2] = v; }
          else if (l15 == 1) { out[(grow * HORIZON + t) * 2 + 1] = v; mul[row * 2 + 1] = v; }
          else if (l15 == 2) { float cx = fminf(fmaxf(v, 0.2f), 1.0f); out[MU_N + (grow * HORIZON + t) * 4] = cx; }
          else if (l15 == 3) { float cc = fminf(fmaxf(v, -0.1f), 0.1f);
                               out[MU_N + (grow * HORIZON + t) * 4 + 1] = cc;
                               out[MU_N + (grow * HORIZON + t) * 4 + 2] = cc; }
          else if (l15 == 4) { float cy = fminf(fmaxf(v, 0.2f), 1.0f); out[MU_N + (grow * HORIZON + t) * 4 + 3] = cy; }
        }
    }
    __syncthreads();  // C: mu for next step visible
  }
}

extern "C" void kernel_launch(void* const* d_in, const int* in_sizes, int n_in,
                              void* d_out, int out_size, void* d_ws, size_t ws_size,
                              hipStream_t stream) {
  const float* zh      = (const float*)d_in[0];
  const float* W_hinit = (const float*)d_in[1];
  const float* b_hinit = (const float*)d_in[2];
  const float* W_ih    = (const float*)d_in[3];
  const float* b_ih    = (const float*)d_in[4];
  const float* W_hh    = (const float*)d_in[5];
  const float* b_hh    = (const float*)d_in[6];
  const float* W_mu    = (const float*)d_in[7];
  const float* b_mu    = (const float*)d_in[8];
  const float* W_cov   = (const float*)d_in[9];
  const float* b_cov   = (const float*)d_in[10];
  float* out = (float*)d_out;
  char* ws = (char*)d_ws;
  u16* whh_b    = (u16*)(ws + WS_WHH);
  u16* wiha_b   = (u16*)(ws + WS_WIHA);
  u16* whinit_b = (u16*)(ws + WS_WHINIT);
  u16* gi       = (u16*)(ws + WS_GI);

  cvt_whh<<<768, 256, 0, stream>>>(W_hh, whh_b);
  cvt_wiha<<<768, 384, 0, stream>>>(W_ih, wiha_b);
  cvt_whinit<<<384, 256, 0, stream>>>(W_hinit, whinit_b);

  hipFuncSetAttribute(reinterpret_cast<const void*>(traj_main),
                      hipFuncAttributeMaxDynamicSharedMemorySize, LDS_TOTAL);
  traj_main<<<GRIDN, NTHR, LDS_TOTAL, stream>>>(
      zh, b_hinit, W_ih, b_ih, b_hh, W_mu, b_mu, W_cov, b_cov,
      whh_b, wiha_b, whinit_b, gi, out);
}

// Round 4
// 6812.740 us; speedup vs baseline: 1.1606x; 1.1606x over previous
//
#include <hip/hip_runtime.h>

typedef short s16x8 __attribute__((ext_vector_type(8)));
typedef float f32x4 __attribute__((ext_vector_type(4)));
typedef unsigned int u32;
typedef unsigned short u16;
typedef u32 u32x4 __attribute__((ext_vector_type(4)));
typedef u16 u16x4 __attribute__((ext_vector_type(4)));

#define DEVI static __device__ __forceinline__

constexpr int HORIZON = 30;
constexpr int BATCH = 65536;
constexpr int INDIM = 384;
constexpr int DEC = 256;
constexpr int G3 = 768;
constexpr int BM = 256;          // batch rows per block
constexpr int NTHR = 512;        // 8 waves
constexpr int NW = 8;
constexpr int GRIDN = BATCH / BM;  // 256 blocks = 1 per CU (persistent)
constexpr long MU_N = (long)BATCH * HORIZON * 2;   // offset of cov in out

// LDS layout (bytes)
constexpr int H_STRIDE = 528;                     // 256 bf16 cols + 8 pad cols
constexpr int ST_STRIDE = 784;                    // staging: 384 bf16 cols + pad
constexpr int LDS_GT    = 256 * H_STRIDE;         // 135168: gatetab [768][4] f32 {wx,wy,bhh,bih}
constexpr int LDS_WOUTB = LDS_GT + G3 * 16;       // 147456: wout bf16 [5][256] = 2560 B
constexpr int LDS_BH0   = LDS_WOUTB + 2560;       // 150016: b_hinit [256] f32
constexpr int LDS_MU    = LDS_BH0 + 1024;         // 151040: mu [256][2] f32
constexpr int LDS_BOUT  = LDS_MU + 2048;          // 153088: bout [8] f32
constexpr int LDS_TOTAL = LDS_BOUT + 32;          // 153120 <= 163840

// workspace layout (bytes)
constexpr size_t WS_WHH    = 0;                       // [768][256] bf16 = 393216
constexpr size_t WS_WIHA   = 393216;                  // [768][384] bf16 = 589824
constexpr size_t WS_WHINIT = 983040;                  // [256][384] bf16 = 196608
constexpr size_t WS_GI     = 1179648;                 // [256 blk][8 wave][3072 uint4]

DEVI f32x4 mfma(s16x8 a, s16x8 b, f32x4 c) {
  return __builtin_amdgcn_mfma_f32_16x16x32_bf16(a, b, c, 0, 0, 0);
}
DEVI u16 f2b(float f) {
  u32 u = __builtin_bit_cast(u32, f);
  u32 r = (u + 0x7fff + ((u >> 16) & 1)) >> 16;
  return (u16)r;
}
DEVI u32 pack2(float lo, float hi) { return (u32)f2b(lo) | ((u32)f2b(hi) << 16); }
DEVI float gilo(u32 u) { return __builtin_bit_cast(float, u << 16); }
DEVI float gihi(u32 u) { return __builtin_bit_cast(float, u & 0xFFFF0000u); }
DEVI float sigm(float x) { return 1.0f / (1.0f + __expf(-x)); }
DEVI float tanh_(float x) { return 1.0f - 2.0f / (__expf(2.0f * x) + 1.0f); }

// ---------------- setup kernels: convert weights to bf16 ----------------
extern "C" __global__ void cvt_whh(const float* __restrict__ in, u16* __restrict__ out) {
  int i = blockIdx.x * 256 + threadIdx.x;
  out[i] = f2b(in[i]);
}
extern "C" __global__ void cvt_wiha(const float* __restrict__ in, u16* __restrict__ out) {
  int j = blockIdx.x, k = threadIdx.x;
  out[j * 384 + k] = f2b(in[j * 386 + k]);
}
extern "C" __global__ void cvt_whinit(const float* __restrict__ in, u16* __restrict__ out) {
  int i = blockIdx.x * 256 + threadIdx.x;
  out[i] = f2b(in[i]);
}

// ---------------- main persistent kernel ----------------
extern "C" __global__ void __launch_bounds__(NTHR, 2)
traj_main(const float* __restrict__ zh, const float* __restrict__ b_hinit,
          const float* __restrict__ W_ih, const float* __restrict__ b_ih,
          const float* __restrict__ b_hh,
          const float* __restrict__ W_mu, const float* __restrict__ b_mu,
          const float* __restrict__ W_cov, const float* __restrict__ b_cov,
          const u16* __restrict__ whh, const u16* __restrict__ wiha,
          const u16* __restrict__ whinit,
          u16* __restrict__ gi_ws, float* __restrict__ out) {
  extern __shared__ char smem[];
  const int tid = threadIdx.x;
  const int lane = tid & 63;
  const int w = tid >> 6;
  const int wm = w & 1;         // row half: rows [wm*128, +128)
  const int wn = w >> 1;        // gate-col quarter
  const int q = lane >> 4;
  const int l15 = lane & 15;
  const int blk = blockIdx.x;
  const long rowg0 = (long)blk * BM;

  float* gt = (float*)(smem + LDS_GT);
  u16* woutb = (u16*)(smem + LDS_WOUTB);
  float* bh0 = (float*)(smem + LDS_BH0);
  float* mul = (float*)(smem + LDS_MU);
  float* bo = (float*)(smem + LDS_BOUT);

  // ---- misc LDS fill
  for (int j = tid; j < G3; j += NTHR) {
    f32x4 v;
    v.x = W_ih[j * 386 + 384]; v.y = W_ih[j * 386 + 385];
    v.z = b_hh[j];             v.w = b_ih[j];
    *(f32x4*)(gt + j * 4) = v;
  }
  for (int idx = tid; idx < 5 * 256; idx += NTHR) {
    int o = idx >> 8, cc = idx & 255;
    float v = (o < 2) ? W_mu[o * 256 + cc] : W_cov[(o - 2) * 256 + cc];
    woutb[idx] = f2b(v);
  }
  if (tid < 256) bh0[tid] = b_hinit[tid];
  if (tid < 8) bo[tid] = (tid < 2) ? b_mu[tid] : (tid < 5 ? b_cov[tid - 2] : 0.0f);

  // hh: persistent per-lane h (bf16 pairs). hh[c*16+m*2+p] = h[wm*128+m*16+q*4+2p .. +1][wn*64+c*16+l15]
  u32 hh[64];
  u32x4* gi4w = (u32x4*)(gi_ws) + (size_t)(blk * NW + w) * 3072;

  // ---- phase A: gi = zh@W_ihA^T + b_ih (to ws), h0 = zh@W_hinit^T + b_hinit (to hh)
  for (int half = 0; half < 2; ++half) {
    __syncthreads();
    {  // stage zh rows [half*128, +128) as bf16 into staging region (aliases h)
      const float4* src = (const float4*)(zh + (rowg0 + half * 128) * INDIM);
      #pragma unroll
      for (int i = 0; i < 24; ++i) {
        int f = tid + i * NTHR;
        int row = f / 96, c4 = f - row * 96;
        float4 v = src[row * 96 + c4];
        u16x4 p; p.x = f2b(v.x); p.y = f2b(v.y); p.z = f2b(v.z); p.w = f2b(v.w);
        *(u16x4*)(smem + row * ST_STRIDE + c4 * 8) = p;
      }
    }
    __syncthreads();
    if (wm == half) {
      // gi chunks: 4 chunks x (3 gates x 16 cols), K=384
      for (int c = 0; c < 4; ++c) {
        f32x4 acc[3][8];
        #pragma unroll
        for (int g = 0; g < 3; ++g)
          #pragma unroll
          for (int m = 0; m < 8; ++m) acc[g][m] = (f32x4)(0.0f);
        #pragma unroll
        for (int kb = 0; kb < 12; ++kb) {
          s16x8 a[8];
          #pragma unroll
          for (int m = 0; m < 8; ++m)
            a[m] = *(const s16x8*)(smem + (m * 16 + l15) * ST_STRIDE + kb * 64 + q * 16);
          #pragma unroll
          for (int g = 0; g < 3; ++g) {
            int cg = g * 256 + wn * 64 + c * 16 + l15;
            s16x8 bb = *(const s16x8*)(wiha + cg * INDIM + kb * 32 + q * 8);
            #pragma unroll
            for (int m = 0; m < 8; ++m) acc[g][m] = mfma(a[m], bb, acc[g][m]);
          }
        }
        int colc = wn * 64 + c * 16 + l15;
        float bi0 = gt[(0 * 256 + colc) * 4 + 3];
        float bi1 = gt[(1 * 256 + colc) * 4 + 3];
        float bi2 = gt[(2 * 256 + colc) * 4 + 3];
        #pragma unroll
        for (int mp = 0; mp < 4; ++mp) {
          #pragma unroll
          for (int g = 0; g < 3; ++g) {
            float bi = (g == 0) ? bi0 : (g == 1) ? bi1 : bi2;
            u32x4 st;
            st.x = pack2(acc[g][mp * 2][0] + bi,     acc[g][mp * 2][1] + bi);
            st.y = pack2(acc[g][mp * 2][2] + bi,     acc[g][mp * 2][3] + bi);
            st.z = pack2(acc[g][mp * 2 + 1][0] + bi, acc[g][mp * 2 + 1][1] + bi);
            st.w = pack2(acc[g][mp * 2 + 1][2] + bi, acc[g][mp * 2 + 1][3] + bi);
            gi4w[(c * 12 + mp * 3 + g) * 64 + lane] = st;
          }
        }
      }
      // h0 chunks: 2 chunks x 32 cols, K=384 -> into hh
      for (int hc = 0; hc < 2; ++hc) {
        f32x4 acc[2][8];
        #pragma unroll
        for (int nt = 0; nt < 2; ++nt)
          #pragma unroll
          for (int m = 0; m < 8; ++m) acc[nt][m] = (f32x4)(0.0f);
        #pragma unroll
        for (int kb = 0; kb < 12; ++kb) {
          s16x8 a[8];
          #pragma unroll
          for (int m = 0; m < 8; ++m)
            a[m] = *(const s16x8*)(smem + (m * 16 + l15) * ST_STRIDE + kb * 64 + q * 16);
          #pragma unroll
          for (int nt = 0; nt < 2; ++nt) {
            int col = wn * 64 + hc * 32 + nt * 16 + l15;
            s16x8 bb = *(const s16x8*)(whinit + col * INDIM + kb * 32 + q * 8);
            #pragma unroll
            for (int m = 0; m < 8; ++m) acc[nt][m] = mfma(a[m], bb, acc[nt][m]);
          }
        }
        #pragma unroll
        for (int nt = 0; nt < 2; ++nt) {
          float bias = bh0[wn * 64 + hc * 32 + nt * 16 + l15];
          #pragma unroll
          for (int m = 0; m < 8; ++m) {
            int ci = hc * 2 + nt;
            hh[ci * 16 + m * 2 + 0] = pack2(acc[nt][m][0] + bias, acc[nt][m][1] + bias);
            hh[ci * 16 + m * 2 + 1] = pack2(acc[nt][m][2] + bias, acc[nt][m][3] + bias);
          }
        }
      }
    }
  }
  __syncthreads();  // staging dead -> h region writable
  // write h0 (in hh) into h_lds
  #pragma unroll
  for (int c = 0; c < 4; ++c)
    #pragma unroll
    for (int m = 0; m < 8; ++m)
      #pragma unroll
      for (int p = 0; p < 2; ++p) {
        u32 v = hh[c * 16 + m * 2 + p];
        int row0 = wm * 128 + m * 16 + q * 4 + p * 2;
        int colh = wn * 64 + c * 16 + l15;
        *(u16*)(smem + row0 * H_STRIDE + colh * 2) = (u16)(v & 0xFFFF);
        *(u16*)(smem + (row0 + 1) * H_STRIDE + colh * 2) = (u16)(v >> 16);
      }
  if (tid < 512) mul[tid] = 0.0f;  // mu0 = 0
  __syncthreads();

  const u32x4* gi4 = (const u32x4*)(gi_ws) + (size_t)(blk * NW + w) * 3072;

  // ---- phase B: 30 recurrent steps
  #pragma unroll 1
  for (int t = 0; t < HORIZON; ++t) {
    #pragma unroll
    for (int c = 0; c < 4; ++c) {
      f32x4 acc[3][8];
      #pragma unroll
      for (int g = 0; g < 3; ++g)
        #pragma unroll
        for (int m = 0; m < 8; ++m) acc[g][m] = (f32x4)(0.0f);
      #pragma unroll
      for (int kb = 0; kb < 8; ++kb) {
        s16x8 a[8];
        #pragma unroll
        for (int m = 0; m < 8; ++m)
          a[m] = *(const s16x8*)(smem + (wm * 128 + m * 16 + l15) * H_STRIDE + kb * 64 + q * 16);
        #pragma unroll
        for (int g = 0; g < 3; ++g) {
          s16x8 bb = *(const s16x8*)(whh + (g * 256 + wn * 64 + c * 16 + l15) * DEC + kb * 32 + q * 8);
          #pragma unroll
          for (int m = 0; m < 8; ++m) acc[g][m] = mfma(a[m], bb, acc[g][m]);
        }
      }
      // epilogue: gates -> h_next (into hh; hh also supplies h_prev)
      int colh = wn * 64 + c * 16 + l15;
      f32x4 tabR = *(const f32x4*)(gt + (0 * 256 + colh) * 4);
      f32x4 tabZ = *(const f32x4*)(gt + (1 * 256 + colh) * 4);
      f32x4 tabN = *(const f32x4*)(gt + (2 * 256 + colh) * 4);
      #pragma unroll
      for (int mp = 0; mp < 4; ++mp) {
        u32x4 gvR = gi4[(c * 12 + mp * 3 + 0) * 64 + lane];
        u32x4 gvZ = gi4[(c * 12 + mp * 3 + 1) * 64 + lane];
        u32x4 gvN = gi4[(c * 12 + mp * 3 + 2) * 64 + lane];
        #pragma unroll
        for (int mh = 0; mh < 2; ++mh) {
          const int m = mp * 2 + mh;
          int row0 = wm * 128 + m * 16 + q * 4;
          f32x4 muA = *(const f32x4*)(mul + row0 * 2);        // rows r=0,1
          f32x4 muB = *(const f32x4*)(mul + row0 * 2 + 4);    // rows r=2,3
          #pragma unroll
          for (int p = 0; p < 2; ++p) {
            float mx0 = p ? muB.x : muA.x, my0 = p ? muB.y : muA.y;
            float mx1 = p ? muB.z : muA.z, my1 = p ? muB.w : muA.w;
            u32 gR = gvR[mh * 2 + p], gZ = gvZ[mh * 2 + p], gN = gvN[mh * 2 + p];
            const int r0 = p * 2, r1 = p * 2 + 1;
            float rin0 = acc[0][m][r0] + tabR.z + gilo(gR) + mx0 * tabR.x + my0 * tabR.y;
            float rin1 = acc[0][m][r1] + tabR.z + gihi(gR) + mx1 * tabR.x + my1 * tabR.y;
            float zin0 = acc[1][m][r0] + tabZ.z + gilo(gZ) + mx0 * tabZ.x + my0 * tabZ.y;
            float zin1 = acc[1][m][r1] + tabZ.z + gihi(gZ) + mx1 * tabZ.x + my1 * tabZ.y;
            float hn0 = acc[2][m][r0] + tabN.z;
            float hn1 = acc[2][m][r1] + tabN.z;
            float rr0 = sigm(rin0), rr1 = sigm(rin1);
            float zz0 = sigm(zin0), zz1 = sigm(zin1);
            float nin0 = gilo(gN) + mx0 * tabN.x + my0 * tabN.y + rr0 * hn0;
            float nin1 = gihi(gN) + mx1 * tabN.x + my1 * tabN.y + rr1 * hn1;
            float nn0 = tanh_(nin0), nn1 = tanh_(nin1);
            u32 hold = hh[c * 16 + m * 2 + p];
            float hp0 = __builtin_bit_cast(float, hold << 16);
            float hp1 = __builtin_bit_cast(float, hold & 0xFFFF0000u);
            float hv0 = nn0 + zz0 * (hp0 - nn0);
            float hv1 = nn1 + zz1 * (hp1 - nn1);
            hh[c * 16 + m * 2 + p] = pack2(hv0, hv1);
          }
        }
      }
    }
    __syncthreads();  // A: all waves done reading h
    #pragma unroll
    for (int c = 0; c < 4; ++c)
      #pragma unroll
      for (int m = 0; m < 8; ++m)
        #pragma unroll
        for (int p = 0; p < 2; ++p) {
          u32 v = hh[c * 16 + m * 2 + p];
          int row0 = wm * 128 + m * 16 + q * 4 + p * 2;
          int colh = wn * 64 + c * 16 + l15;
          *(u16*)(smem + row0 * H_STRIDE + colh * 2) = (u16)(v & 0xFFFF);
          *(u16*)(smem + (row0 + 1) * H_STRIDE + colh * 2) = (u16)(v >> 16);
        }
    __syncthreads();  // B: h_next visible
    // mu/cov GEMV via MFMA: out5 = h @ [W_mu;W_cov]^T (bf16 weights from LDS)
    {
      f32x4 acc2[2] = {(f32x4)(0.0f), (f32x4)(0.0f)};
      #pragma unroll
      for (int kb = 0; kb < 8; ++kb) {
        s16x8 bb = {0, 0, 0, 0, 0, 0, 0, 0};
        if (l15 < 5) bb = *(const s16x8*)(woutb + l15 * 256 + kb * 32 + q * 8);
        #pragma unroll
        for (int m = 0; m < 2; ++m) {
          s16x8 a = *(const s16x8*)(smem + (w * 32 + m * 16 + l15) * H_STRIDE + kb * 64 + q * 16);
          acc2[m] = mfma(a, bb, acc2[m]);
        }
      }
      float bias = (l15 < 5) ? bo[l15] : 0.0f;
      #pragma unroll
      for (int m = 0; m < 2; ++m)
        #pragma unroll
        for (int r = 0; r < 4; ++r) {
          int row = w * 32 + m * 16 + q * 4 + r;
          long grow = rowg0 + row;
          float v = acc2[m][r] + bias;
          if (l15 == 0) { out[(grow * HORIZON + t) * 2] = v; mul[row * 2] = v; }
          else if (l15 == 1) { out[(grow * HORIZON + t) * 2 + 1] = v; mul[row * 2 + 1] = v; }
          else if (l15 == 2) { float cx = fminf(fmaxf(v, 0.2f), 1.0f); out[MU_N + (grow * HORIZON + t) * 4] = cx; }
          else if (l15 == 3) { float cc = fminf(fmaxf(v, -0.1f), 0.1f);
                               out[MU_N + (grow * HORIZON + t) * 4 + 1] = cc;
                               out[MU_N + (grow * HORIZON + t) * 4 + 2] = cc; }
          else if (l15 == 4) { float cy = fminf(fmaxf(v, 0.2f), 1.0f); out[MU_N + (grow * HORIZON + t) * 4 + 3] = cy; }
        }
    }
    __syncthreads();  // C: mu for next step visible
  }
}

extern "C" void kernel_launch(void* const* d_in, const int* in_sizes, int n_in,
                              void* d_out, int out_size, void* d_ws, size_t ws_size,
                              hipStream_t stream) {
  const float* zh      = (const float*)d_in[0];
  const float* W_hinit = (const float*)d_in[1];
  const float* b_hinit = (const float*)d_in[2];
  const float* W_ih    = (const float*)d_in[3];
  const float* b_ih    = (const float*)d_in[4];
  const float* W_hh    = (const float*)d_in[5];
  const float* b_hh    = (const float*)d_in[6];
  const float* W_mu    = (const float*)d_in[7];
  const float* b_mu    = (const float*)d_in[8];
  const float* W_cov   = (const float*)d_in[9];
  const float* b_cov   = (const float*)d_in[10];
  float* out = (float*)d_out;
  char* ws = (char*)d_ws;
  u16* whh_b    = (u16*)(ws + WS_WHH);
  u16* wiha_b   = (u16*)(ws + WS_WIHA);
  u16* whinit_b = (u16*)(ws + WS_WHINIT);
  u16* gi       = (u16*)(ws + WS_GI);

  cvt_whh<<<768, 256, 0, stream>>>(W_hh, whh_b);
  cvt_wiha<<<768, 384, 0, stream>>>(W_ih, wiha_b);
  cvt_whinit<<<384, 256, 0, stream>>>(W_hinit, whinit_b);

  hipFuncSetAttribute(reinterpret_cast<const void*>(traj_main),
                      hipFuncAttributeMaxDynamicSharedMemorySize, LDS_TOTAL);
  traj_main<<<GRIDN, NTHR, LDS_TOTAL, stream>>>(
      zh, b_hinit, W_ih, b_ih, b_hh, W_mu, b_mu, W_cov, b_cov,
      whh_b, wiha_b, whinit_b, gi, out);
}

// Round 8
// 3291.254 us; speedup vs baseline: 2.4024x; 2.0700x over previous
//
#include <hip/hip_runtime.h>

typedef short s16x8 __attribute__((ext_vector_type(8)));
typedef float f32x4 __attribute__((ext_vector_type(4)));
typedef unsigned int u32;
typedef unsigned short u16;
typedef u32 u32x4 __attribute__((ext_vector_type(4)));
typedef u16 u16x4 __attribute__((ext_vector_type(4)));

#define DEVI static __device__ __forceinline__

constexpr int HORIZON = 30;
constexpr int BATCH = 65536;
constexpr int INDIM = 384;
constexpr int DEC = 256;
constexpr int G3 = 768;
constexpr int BM = 128;            // batch rows per block
constexpr int NTHR = 512;          // 8 waves
constexpr int NW = 8;
constexpr int GRIDN = BATCH / BM;  // 512 blocks (1/CU resident, 2 rounds)
constexpr long MU_N = (long)BATCH * HORIZON * 2;   // offset of cov in out

// LDS layout (bytes)
constexpr int H_STRIDE = 528;                     // 256 bf16 cols + 8 pad cols (2-way bank alias only)
constexpr int ST_STRIDE = 784;                    // staging: 384 bf16 cols + pad
constexpr int HBUF = BM * H_STRIDE;               // 67584 per h buffer
constexpr int LDS_GT    = 2 * HBUF;               // 135168: gatetab [768][4] f32 {wx,wy,bhh,bih}
constexpr int LDS_WOUTB = LDS_GT + G3 * 16;       // 147456: wout bf16 [5][256]
constexpr int LDS_BH0   = LDS_WOUTB + 2560;       // 150016: b_hinit [256] f32
constexpr int LDS_MU    = LDS_BH0 + 1024;         // 151040: mu [128][2] f32
constexpr int LDS_BOUT  = LDS_MU + BM * 8;        // 152064: bout [8] f32
constexpr int LDS_TOTAL = LDS_BOUT + 32;          // 152096 <= 163840  (1 block/CU)

// workspace layout (bytes)
constexpr size_t WS_WHH    = 0;                       // [768][256] bf16
constexpr size_t WS_WIHA   = 393216;                  // [768][384] bf16
constexpr size_t WS_WHINIT = 983040;                  // [256][384] bf16
constexpr size_t WS_GI     = 1179648;                 // [512 blk][8 wave][1536 uint4]

DEVI f32x4 mfma(s16x8 a, s16x8 b, f32x4 c) {
  return __builtin_amdgcn_mfma_f32_16x16x32_bf16(a, b, c, 0, 0, 0);
}
DEVI u16 f2b(float f) {
  u32 u = __builtin_bit_cast(u32, f);
  u32 r = (u + 0x7fff + ((u >> 16) & 1)) >> 16;
  return (u16)r;
}
DEVI float b2f(u16 s) { return __builtin_bit_cast(float, ((u32)s) << 16); }
DEVI u32 pack2(float lo, float hi) { return (u32)f2b(lo) | ((u32)f2b(hi) << 16); }
DEVI float gilo(u32 u) { return __builtin_bit_cast(float, u << 16); }
DEVI float gihi(u32 u) { return __builtin_bit_cast(float, u & 0xFFFF0000u); }
DEVI float sigm(float x) { return 1.0f / (1.0f + __expf(-x)); }
DEVI float tanh_(float x) { return 1.0f - 2.0f / (__expf(2.0f * x) + 1.0f); }

// ---------------- setup kernels: convert weights to bf16 ----------------
extern "C" __global__ void cvt_whh(const float* __restrict__ in, u16* __restrict__ out) {
  int i = blockIdx.x * 256 + threadIdx.x;
  out[i] = f2b(in[i]);
}
extern "C" __global__ void cvt_wiha(const float* __restrict__ in, u16* __restrict__ out) {
  int j = blockIdx.x, k = threadIdx.x;
  out[j * 384 + k] = f2b(in[j * 386 + k]);
}
extern "C" __global__ void cvt_whinit(const float* __restrict__ in, u16* __restrict__ out) {
  int i = blockIdx.x * 256 + threadIdx.x;
  out[i] = f2b(in[i]);
}

// ---------------- main kernel ----------------
extern "C" __global__ void __launch_bounds__(NTHR, 2)
traj_main(const float* __restrict__ zh, const float* __restrict__ b_hinit,
          const float* __restrict__ W_ih, const float* __restrict__ b_ih,
          const float* __restrict__ b_hh,
          const float* __restrict__ W_mu, const float* __restrict__ b_mu,
          const float* __restrict__ W_cov, const float* __restrict__ b_cov,
          const u16* __restrict__ whh, const u16* __restrict__ wiha,
          const u16* __restrict__ whinit,
          u16* __restrict__ gi_ws, float* __restrict__ out) {
  extern __shared__ char smem[];
  const int tid = threadIdx.x;
  const int lane = tid & 63;
  const int w = tid >> 6;
  const int wm = w & 1;         // row half: rows [wm*64, +64)
  const int wn = w >> 1;        // gate-col quarter: cols [wn*64, +64) per gate
  const int q = lane >> 4;
  const int l15 = lane & 15;
  const int blk = blockIdx.x;
  const long rowg0 = (long)blk * BM;

  float* gt = (float*)(smem + LDS_GT);
  u16* woutb = (u16*)(smem + LDS_WOUTB);
  float* bh0 = (float*)(smem + LDS_BH0);
  float* mul = (float*)(smem + LDS_MU);
  float* bo = (float*)(smem + LDS_BOUT);

  // ---- misc LDS fill (disjoint from staging region)
  for (int j = tid; j < G3; j += NTHR) {
    f32x4 v;
    v.x = W_ih[j * 386 + 384]; v.y = W_ih[j * 386 + 385];
    v.z = b_hh[j];             v.w = b_ih[j];
    *(f32x4*)(gt + j * 4) = v;
  }
  for (int idx = tid; idx < 5 * 256; idx += NTHR) {
    int o = idx >> 8, cc = idx & 255;
    float v = (o < 2) ? W_mu[o * 256 + cc] : W_cov[(o - 2) * 256 + cc];
    woutb[idx] = f2b(v);
  }
  if (tid < 256) bh0[tid] = b_hinit[tid];
  if (tid < 8) bo[tid] = (tid < 2) ? b_mu[tid] : (tid < 5 ? b_cov[tid - 2] : 0.0f);

  // ---- stage all 128 zh rows as bf16 (aliases both h buffers; h not live yet)
  {
    const float4* src = (const float4*)(zh + rowg0 * INDIM);
    #pragma unroll
    for (int i = 0; i < 24; ++i) {
      int f = tid + i * NTHR;                 // 0..12287
      int row = f / 96, c4 = f - row * 96;
      float4 v = src[row * 96 + c4];
      u16x4 p; p.x = f2b(v.x); p.y = f2b(v.y); p.z = f2b(v.z); p.w = f2b(v.w);
      *(u16x4*)(smem + row * ST_STRIDE + c4 * 8) = p;
    }
  }
  __syncthreads();

  u32x4* gi4w = (u32x4*)(gi_ws) + (size_t)(blk * NW + w) * 1536;

  // ---- phase A1: gi = zh@W_ihA^T + b_ih -> ws (packed for phase-B tile order)
  for (int c = 0; c < 4; ++c) {
    f32x4 acc[3][4];
    #pragma unroll
    for (int g = 0; g < 3; ++g)
      #pragma unroll
      for (int m = 0; m < 4; ++m) acc[g][m] = (f32x4)(0.0f);
    #pragma unroll
    for (int kb = 0; kb < 12; ++kb) {
      s16x8 a[4];
      #pragma unroll
      for (int m = 0; m < 4; ++m)
        a[m] = *(const s16x8*)(smem + (wm * 64 + m * 16 + l15) * ST_STRIDE + kb * 64 + q * 16);
      #pragma unroll
      for (int g = 0; g < 3; ++g) {
        int cg = g * 256 + wn * 64 + c * 16 + l15;
        s16x8 bb = *(const s16x8*)(wiha + cg * INDIM + kb * 32 + q * 8);
        #pragma unroll
        for (int m = 0; m < 4; ++m) acc[g][m] = mfma(a[m], bb, acc[g][m]);
      }
    }
    int colc = wn * 64 + c * 16 + l15;
    #pragma unroll
    for (int mp = 0; mp < 2; ++mp) {
      #pragma unroll
      for (int g = 0; g < 3; ++g) {
        float bi = gt[(g * 256 + colc) * 4 + 3];
        u32x4 st;
        st.x = pack2(acc[g][mp * 2][0] + bi,     acc[g][mp * 2][1] + bi);
        st.y = pack2(acc[g][mp * 2][2] + bi,     acc[g][mp * 2][3] + bi);
        st.z = pack2(acc[g][mp * 2 + 1][0] + bi, acc[g][mp * 2 + 1][1] + bi);
        st.w = pack2(acc[g][mp * 2 + 1][2] + bi, acc[g][mp * 2 + 1][3] + bi);
        gi4w[(c * 6 + mp * 3 + g) * 64 + lane] = st;
      }
    }
  }

  // ---- phase A2: h0 = zh@W_hinit^T + b_hinit (64 rows x 64 cols per wave)
  u32 h0r[32];
  {
    f32x4 acc[4][4];
    #pragma unroll
    for (int nf = 0; nf < 4; ++nf)
      #pragma unroll
      for (int m = 0; m < 4; ++m) acc[nf][m] = (f32x4)(0.0f);
    #pragma unroll
    for (int kb = 0; kb < 12; ++kb) {
      s16x8 a[4];
      #pragma unroll
      for (int m = 0; m < 4; ++m)
        a[m] = *(const s16x8*)(smem + (wm * 64 + m * 16 + l15) * ST_STRIDE + kb * 64 + q * 16);
      #pragma unroll
      for (int nf = 0; nf < 4; ++nf) {
        int col = wn * 64 + nf * 16 + l15;
        s16x8 bb = *(const s16x8*)(whinit + col * INDIM + kb * 32 + q * 8);
        #pragma unroll
        for (int m = 0; m < 4; ++m) acc[nf][m] = mfma(a[m], bb, acc[nf][m]);
      }
    }
    #pragma unroll
    for (int nf = 0; nf < 4; ++nf) {
      float bias = bh0[wn * 64 + nf * 16 + l15];
      #pragma unroll
      for (int m = 0; m < 4; ++m) {
        h0r[nf * 8 + m * 2]     = pack2(acc[nf][m][0] + bias, acc[nf][m][1] + bias);
        h0r[nf * 8 + m * 2 + 1] = pack2(acc[nf][m][2] + bias, acc[nf][m][3] + bias);
      }
    }
  }
  __syncthreads();  // staging dead -> buffer 0 writable
  #pragma unroll
  for (int nf = 0; nf < 4; ++nf)
    #pragma unroll
    for (int m = 0; m < 4; ++m)
      #pragma unroll
      for (int p = 0; p < 2; ++p) {
        u32 v = h0r[nf * 8 + m * 2 + p];
        int row0 = wm * 64 + m * 16 + q * 4 + p * 2;
        int colh = wn * 64 + nf * 16 + l15;
        *(u16*)(smem + row0 * H_STRIDE + colh * 2) = (u16)(v & 0xFFFF);
        *(u16*)(smem + (row0 + 1) * H_STRIDE + colh * 2) = (u16)(v >> 16);
      }
  if (tid < 256) mul[tid] = 0.0f;  // mu0 = 0 (128 rows x 2)
  __syncthreads();

  const u32x4* gi4 = (const u32x4*)(gi_ws) + (size_t)(blk * NW + w) * 1536;

  // ---- phase B: 30 recurrent steps, h double-buffered in LDS
  #pragma unroll 1
  for (int t = 0; t < HORIZON; ++t) {
    char* cur = smem + (t & 1) * HBUF;
    char* nxt = smem + ((t + 1) & 1) * HBUF;
    #pragma unroll
    for (int c = 0; c < 4; ++c) {
      f32x4 acc[3][4];
      #pragma unroll
      for (int g = 0; g < 3; ++g)
        #pragma unroll
        for (int m = 0; m < 4; ++m) acc[g][m] = (f32x4)(0.0f);
      #pragma unroll
      for (int kb = 0; kb < 8; ++kb) {
        s16x8 a[4];
        #pragma unroll
        for (int m = 0; m < 4; ++m)
          a[m] = *(const s16x8*)(cur + (wm * 64 + m * 16 + l15) * H_STRIDE + kb * 64 + q * 16);
        #pragma unroll
        for (int g = 0; g < 3; ++g) {
          s16x8 bb = *(const s16x8*)(whh + (g * 256 + wn * 64 + c * 16 + l15) * DEC + kb * 32 + q * 8);
          #pragma unroll
          for (int m = 0; m < 4; ++m) acc[g][m] = mfma(a[m], bb, acc[g][m]);
        }
      }
      // epilogue: gates -> h_next written directly into nxt buffer
      int colh = wn * 64 + c * 16 + l15;
      f32x4 tabR = *(const f32x4*)(gt + (0 * 256 + colh) * 4);
      f32x4 tabZ = *(const f32x4*)(gt + (1 * 256 + colh) * 4);
      f32x4 tabN = *(const f32x4*)(gt + (2 * 256 + colh) * 4);
      #pragma unroll
      for (int mp = 0; mp < 2; ++mp) {
        u32x4 gvR = gi4[(c * 6 + mp * 3 + 0) * 64 + lane];
        u32x4 gvZ = gi4[(c * 6 + mp * 3 + 1) * 64 + lane];
        u32x4 gvN = gi4[(c * 6 + mp * 3 + 2) * 64 + lane];
        #pragma unroll
        for (int mh = 0; mh < 2; ++mh) {
          const int m = mp * 2 + mh;
          int row0 = wm * 64 + m * 16 + q * 4;
          f32x4 muA = *(const f32x4*)(mul + row0 * 2);        // rows r=0,1
          f32x4 muB = *(const f32x4*)(mul + row0 * 2 + 4);    // rows r=2,3
          #pragma unroll
          for (int p = 0; p < 2; ++p) {
            float mx0 = p ? muB.x : muA.x, my0 = p ? muB.y : muA.y;
            float mx1 = p ? muB.z : muA.z, my1 = p ? muB.w : muA.w;
            u32 gR = gvR[mh * 2 + p], gZ = gvZ[mh * 2 + p], gN = gvN[mh * 2 + p];
            const int r0 = p * 2, r1 = p * 2 + 1;
            int rowa = row0 + p * 2;
            float hp0 = b2f(*(const u16*)(cur + rowa * H_STRIDE + colh * 2));
            float hp1 = b2f(*(const u16*)(cur + (rowa + 1) * H_STRIDE + colh * 2));
            float rin0 = acc[0][m][r0] + tabR.z + gilo(gR) + mx0 * tabR.x + my0 * tabR.y;
            float rin1 = acc[0][m][r1] + tabR.z + gihi(gR) + mx1 * tabR.x + my1 * tabR.y;
            float zin0 = acc[1][m][r0] + tabZ.z + gilo(gZ) + mx0 * tabZ.x + my0 * tabZ.y;
            float zin1 = acc[1][m][r1] + tabZ.z + gihi(gZ) + mx1 * tabZ.x + my1 * tabZ.y;
            float hn0 = acc[2][m][r0] + tabN.z;
            float hn1 = acc[2][m][r1] + tabN.z;
            float rr0 = sigm(rin0), rr1 = sigm(rin1);
            float zz0 = sigm(zin0), zz1 = sigm(zin1);
            float nin0 = gilo(gN) + mx0 * tabN.x + my0 * tabN.y + rr0 * hn0;
            float nin1 = gihi(gN) + mx1 * tabN.x + my1 * tabN.y + rr1 * hn1;
            float nn0 = tanh_(nin0), nn1 = tanh_(nin1);
            float hv0 = nn0 + zz0 * (hp0 - nn0);
            float hv1 = nn1 + zz1 * (hp1 - nn1);
            *(u16*)(nxt + rowa * H_STRIDE + colh * 2) = f2b(hv0);
            *(u16*)(nxt + (rowa + 1) * H_STRIDE + colh * 2) = f2b(hv1);
          }
        }
      }
    }
    __syncthreads();  // barrier 1: nxt fully written; cur reads done
    // mu/cov GEMV via MFMA on h_next (nxt): each wave owns 16 rows
    {
      f32x4 acc2 = (f32x4)(0.0f);
      #pragma unroll
      for (int kb = 0; kb < 8; ++kb) {
        s16x8 bb = {0, 0, 0, 0, 0, 0, 0, 0};
        if (l15 < 5) bb = *(const s16x8*)(woutb + l15 * 256 + kb * 32 + q * 8);
        s16x8 a = *(const s16x8*)(nxt + (w * 16 + l15) * H_STRIDE + kb * 64 + q * 16);
        acc2 = mfma(a, bb, acc2);
      }
      float bias = (l15 < 5) ? bo[l15] : 0.0f;
      #pragma unroll
      for (int r = 0; r < 4; ++r) {
        int row = w * 16 + q * 4 + r;
        long grow = rowg0 + row;
        float v = acc2[r] + bias;
        if (l15 == 0) { out[(grow * HORIZON + t) * 2] = v; mul[row * 2] = v; }
        else if (l15 == 1) { out[(grow * HORIZON + t) * 2 + 1] = v; mul[row * 2 + 1] = v; }
        else if (l15 == 2) { float cx = fminf(fmaxf(v, 0.2f), 1.0f); out[MU_N + (grow * HORIZON + t) * 4] = cx; }
        else if (l15 == 3) { float cc = fminf(fmaxf(v, -0.1f), 0.1f);
                             out[MU_N + (grow * HORIZON + t) * 4 + 1] = cc;
                             out[MU_N + (grow * HORIZON + t) * 4 + 2] = cc; }
        else if (l15 == 4) { float cy = fminf(fmaxf(v, 0.2f), 1.0f); out[MU_N + (grow * HORIZON + t) * 4 + 3] = cy; }
      }
    }
    __syncthreads();  // barrier 2: mu visible for next step; nxt reads done
  }
}

extern "C" void kernel_launch(void* const* d_in, const int* in_sizes, int n_in,
                              void* d_out, int out_size, void* d_ws, size_t ws_size,
                              hipStream_t stream) {
  const float* zh      = (const float*)d_in[0];
  const float* W_hinit = (const float*)d_in[1];
  const float* b_hinit = (const float*)d_in[2];
  const float* W_ih    = (const float*)d_in[3];
  const float* b_ih    = (const float*)d_in[4];
  const float* W_hh    = (const float*)d_in[5];
  const float* b_hh    = (const float*)d_in[6];
  const float* W_mu    = (const float*)d_in[7];
  const float* b_mu    = (const float*)d_in[8];
  const float* W_cov   = (const float*)d_in[9];
  const float* b_cov   = (const float*)d_in[10];
  float* out = (float*)d_out;
  char* ws = (char*)d_ws;
  u16* whh_b    = (u16*)(ws + WS_WHH);
  u16* wiha_b   = (u16*)(ws + WS_WIHA);
  u16* whinit_b = (u16*)(ws + WS_WHINIT);
  u16* gi       = (u16*)(ws + WS_GI);

  cvt_whh<<<768, 256, 0, stream>>>(W_hh, whh_b);
  cvt_wiha<<<768, 384, 0, stream>>>(W_ih, wiha_b);
  cvt_whinit<<<384, 256, 0, stream>>>(W_hinit, whinit_b);

  hipFuncSetAttribute(reinterpret_cast<const void*>(traj_main),
                      hipFuncAttributeMaxDynamicSharedMemorySize, LDS_TOTAL);
  traj_main<<<GRIDN, NTHR, LDS_TOTAL, stream>>>(
      zh, b_hinit, W_ih, b_ih, b_hh, W_mu, b_mu, W_cov, b_cov,
      whh_b, wiha_b, whinit_b, gi, out);
}

// Round 9
// 2115.526 us; speedup vs baseline: 3.7376x; 1.5558x over previous
//
#include <hip/hip_runtime.h>

typedef short s16x8 __attribute__((ext_vector_type(8)));
typedef float f32x4 __attribute__((ext_vector_type(4)));
typedef unsigned int u32;
typedef unsigned short u16;
typedef u32 u32x4 __attribute__((ext_vector_type(4)));
typedef u16 u16x4 __attribute__((ext_vector_type(4)));

#define DEVI static __device__ __forceinline__

constexpr int HORIZON = 30;
constexpr int BATCH = 65536;
constexpr int INDIM = 384;
constexpr int DEC = 256;
constexpr int G3 = 768;
constexpr int BM = 128;            // batch rows per block
constexpr int NTHR = 512;          // 8 waves
constexpr int NW = 8;
constexpr int GRIDN = BATCH / BM;  // 512 blocks (1/CU resident, 2 rounds)
constexpr long MU_N = (long)BATCH * HORIZON * 2;   // offset of cov in out

// LDS layout (bytes)
constexpr int H_STRIDE = 528;                     // 256 bf16 cols + 8 pad cols (2-way bank alias only)
constexpr int ST_STRIDE = 784;                    // staging: 384 bf16 cols + pad
constexpr int HBUF = BM * H_STRIDE;               // 67584 per h buffer
constexpr int LDS_GT    = 2 * HBUF;               // 135168: gatetab [768][4] f32 {wx,wy,bhh,bih}
constexpr int LDS_WOUTB = LDS_GT + G3 * 16;       // 147456: wout bf16 [5][256]
constexpr int LDS_BH0   = LDS_WOUTB + 2560;       // 150016: b_hinit [256] f32
constexpr int LDS_MU    = LDS_BH0 + 1024;         // 151040: mu [128][2] f32
constexpr int LDS_BOUT  = LDS_MU + BM * 8;        // 152064: bout [8] f32
constexpr int LDS_TOTAL = LDS_BOUT + 32;          // 152096 <= 163840  (1 block/CU)

// workspace layout (bytes)
constexpr size_t WS_WHH    = 0;                       // [768][256] bf16
constexpr size_t WS_WIHA   = 393216;                  // [768][384] bf16
constexpr size_t WS_WHINIT = 983040;                  // [256][384] bf16
constexpr size_t WS_GI     = 1179648;                 // [512 blk][8 wave][1536 uint4]

DEVI f32x4 mfma(s16x8 a, s16x8 b, f32x4 c) {
  return __builtin_amdgcn_mfma_f32_16x16x32_bf16(a, b, c, 0, 0, 0);
}
DEVI u16 f2b(float f) {
  u32 u = __builtin_bit_cast(u32, f);
  u32 r = (u + 0x7fff + ((u >> 16) & 1)) >> 16;
  return (u16)r;
}
DEVI float b2f(u16 s) { return __builtin_bit_cast(float, ((u32)s) << 16); }
DEVI u32 pack2(float lo, float hi) { return (u32)f2b(lo) | ((u32)f2b(hi) << 16); }
DEVI float gilo(u32 u) { return __builtin_bit_cast(float, u << 16); }
DEVI float gihi(u32 u) { return __builtin_bit_cast(float, u & 0xFFFF0000u); }
DEVI float sigm(float x) { return 1.0f / (1.0f + __expf(-x)); }
DEVI float tanh_(float x) { return 1.0f - 2.0f / (__expf(2.0f * x) + 1.0f); }

// ---------------- setup kernels: convert weights to bf16 ----------------
extern "C" __global__ void cvt_whh(const float* __restrict__ in, u16* __restrict__ out) {
  int i = blockIdx.x * 256 + threadIdx.x;
  out[i] = f2b(in[i]);
}
extern "C" __global__ void cvt_wiha(const float* __restrict__ in, u16* __restrict__ out) {
  int j = blockIdx.x, k = threadIdx.x;
  out[j * 384 + k] = f2b(in[j * 386 + k]);
}
extern "C" __global__ void cvt_whinit(const float* __restrict__ in, u16* __restrict__ out) {
  int i = blockIdx.x * 256 + threadIdx.x;
  out[i] = f2b(in[i]);
}

// ---------------- main kernel ----------------
extern "C" __global__ void __launch_bounds__(NTHR, 2)
traj_main(const float* __restrict__ zh, const float* __restrict__ b_hinit,
          const float* __restrict__ W_ih, const float* __restrict__ b_ih,
          const float* __restrict__ b_hh,
          const float* __restrict__ W_mu, const float* __restrict__ b_mu,
          const float* __restrict__ W_cov, const float* __restrict__ b_cov,
          const u16* __restrict__ whh, const u16* __restrict__ wiha,
          const u16* __restrict__ whinit,
          u16* __restrict__ gi_ws, float* __restrict__ out) {
  extern __shared__ char smem[];
  const int tid = threadIdx.x;
  const int lane = tid & 63;
  const int w = tid >> 6;
  const int wm = w & 1;         // row half: rows [wm*64, +64)
  const int wn = w >> 1;        // gate-col quarter: cols [wn*64, +64) per gate
  const int q = lane >> 4;
  const int l15 = lane & 15;
  const int blk = blockIdx.x;
  const long rowg0 = (long)blk * BM;

  float* gt = (float*)(smem + LDS_GT);
  u16* woutb = (u16*)(smem + LDS_WOUTB);
  float* bh0 = (float*)(smem + LDS_BH0);
  float* mul = (float*)(smem + LDS_MU);
  float* bo = (float*)(smem + LDS_BOUT);

  // ---- misc LDS fill (disjoint from staging region)
  for (int j = tid; j < G3; j += NTHR) {
    f32x4 v;
    v.x = W_ih[j * 386 + 384]; v.y = W_ih[j * 386 + 385];
    v.z = b_hh[j];             v.w = b_ih[j];
    *(f32x4*)(gt + j * 4) = v;
  }
  for (int idx = tid; idx < 5 * 256; idx += NTHR) {
    int o = idx >> 8, cc = idx & 255;
    float v = (o < 2) ? W_mu[o * 256 + cc] : W_cov[(o - 2) * 256 + cc];
    woutb[idx] = f2b(v);
  }
  if (tid < 256) bh0[tid] = b_hinit[tid];
  if (tid < 8) bo[tid] = (tid < 2) ? b_mu[tid] : (tid < 5 ? b_cov[tid - 2] : 0.0f);

  // ---- stage all 128 zh rows as bf16 (aliases both h buffers; h not live yet)
  {
    const float4* src = (const float4*)(zh + rowg0 * INDIM);
    #pragma unroll
    for (int i = 0; i < 24; ++i) {
      int f = tid + i * NTHR;                 // 0..12287
      int row = f / 96, c4 = f - row * 96;
      float4 v = src[row * 96 + c4];
      u16x4 p; p.x = f2b(v.x); p.y = f2b(v.y); p.z = f2b(v.z); p.w = f2b(v.w);
      *(u16x4*)(smem + row * ST_STRIDE + c4 * 8) = p;
    }
  }
  __syncthreads();

  u32x4* gi4w = (u32x4*)(gi_ws) + (size_t)(blk * NW + w) * 1536;

  // ---- phase A1: gi = zh@W_ihA^T + b_ih -> ws (packed for phase-B tile order)
  #pragma unroll 1
  for (int c = 0; c < 4; ++c) {
    f32x4 acc[3][4];
    #pragma unroll
    for (int g = 0; g < 3; ++g)
      #pragma unroll
      for (int m = 0; m < 4; ++m) acc[g][m] = (f32x4)(0.0f);
    #pragma unroll
    for (int kb = 0; kb < 12; ++kb) {
      s16x8 a[4];
      #pragma unroll
      for (int m = 0; m < 4; ++m)
        a[m] = *(const s16x8*)(smem + (wm * 64 + m * 16 + l15) * ST_STRIDE + kb * 64 + q * 16);
      #pragma unroll
      for (int g = 0; g < 3; ++g) {
        int cg = g * 256 + wn * 64 + c * 16 + l15;
        s16x8 bb = *(const s16x8*)(wiha + cg * INDIM + kb * 32 + q * 8);
        #pragma unroll
        for (int m = 0; m < 4; ++m) acc[g][m] = mfma(a[m], bb, acc[g][m]);
      }
    }
    int colc = wn * 64 + c * 16 + l15;
    #pragma unroll
    for (int mp = 0; mp < 2; ++mp) {
      #pragma unroll
      for (int g = 0; g < 3; ++g) {
        float bi = gt[(g * 256 + colc) * 4 + 3];
        u32x4 st;
        st.x = pack2(acc[g][mp * 2][0] + bi,     acc[g][mp * 2][1] + bi);
        st.y = pack2(acc[g][mp * 2][2] + bi,     acc[g][mp * 2][3] + bi);
        st.z = pack2(acc[g][mp * 2 + 1][0] + bi, acc[g][mp * 2 + 1][1] + bi);
        st.w = pack2(acc[g][mp * 2 + 1][2] + bi, acc[g][mp * 2 + 1][3] + bi);
        gi4w[(c * 6 + mp * 3 + g) * 64 + lane] = st;
      }
    }
  }

  // ---- phase A2: h0 = zh@W_hinit^T + b_hinit (64 rows x 64 cols per wave)
  u32 h0r[32];
  {
    f32x4 acc[4][4];
    #pragma unroll
    for (int nf = 0; nf < 4; ++nf)
      #pragma unroll
      for (int m = 0; m < 4; ++m) acc[nf][m] = (f32x4)(0.0f);
    #pragma unroll
    for (int kb = 0; kb < 12; ++kb) {
      s16x8 a[4];
      #pragma unroll
      for (int m = 0; m < 4; ++m)
        a[m] = *(const s16x8*)(smem + (wm * 64 + m * 16 + l15) * ST_STRIDE + kb * 64 + q * 16);
      #pragma unroll
      for (int nf = 0; nf < 4; ++nf) {
        int col = wn * 64 + nf * 16 + l15;
        s16x8 bb = *(const s16x8*)(whinit + col * INDIM + kb * 32 + q * 8);
        #pragma unroll
        for (int m = 0; m < 4; ++m) acc[nf][m] = mfma(a[m], bb, acc[nf][m]);
      }
    }
    #pragma unroll
    for (int nf = 0; nf < 4; ++nf) {
      float bias = bh0[wn * 64 + nf * 16 + l15];
      #pragma unroll
      for (int m = 0; m < 4; ++m) {
        h0r[nf * 8 + m * 2]     = pack2(acc[nf][m][0] + bias, acc[nf][m][1] + bias);
        h0r[nf * 8 + m * 2 + 1] = pack2(acc[nf][m][2] + bias, acc[nf][m][3] + bias);
      }
    }
  }
  __syncthreads();  // staging dead -> buffer 0 writable
  #pragma unroll
  for (int nf = 0; nf < 4; ++nf)
    #pragma unroll
    for (int m = 0; m < 4; ++m)
      #pragma unroll
      for (int p = 0; p < 2; ++p) {
        u32 v = h0r[nf * 8 + m * 2 + p];
        int row0 = wm * 64 + m * 16 + q * 4 + p * 2;
        int colh = wn * 64 + nf * 16 + l15;
        *(u16*)(smem + row0 * H_STRIDE + colh * 2) = (u16)(v & 0xFFFF);
        *(u16*)(smem + (row0 + 1) * H_STRIDE + colh * 2) = (u16)(v >> 16);
      }
  if (tid < 256) mul[tid] = 0.0f;  // mu0 = 0 (128 rows x 2)
  __syncthreads();

  const u32x4* gi4 = (const u32x4*)(gi_ws) + (size_t)(blk * NW + w) * 1536;

  // ---- phase B: 30 recurrent steps, h double-buffered in LDS
  #pragma unroll 1
  for (int t = 0; t < HORIZON; ++t) {
    char* cur = smem + (t & 1) * HBUF;
    char* nxt = smem + ((t + 1) & 1) * HBUF;
    #pragma unroll 1
    for (int c = 0; c < 4; ++c) {
      f32x4 acc[3][4];
      #pragma unroll
      for (int g = 0; g < 3; ++g)
        #pragma unroll
        for (int m = 0; m < 4; ++m) acc[g][m] = (f32x4)(0.0f);
      #pragma unroll
      for (int kb = 0; kb < 8; ++kb) {
        s16x8 a[4];
        #pragma unroll
        for (int m = 0; m < 4; ++m)
          a[m] = *(const s16x8*)(cur + (wm * 64 + m * 16 + l15) * H_STRIDE + kb * 64 + q * 16);
        #pragma unroll
        for (int g = 0; g < 3; ++g) {
          s16x8 bb = *(const s16x8*)(whh + (g * 256 + wn * 64 + c * 16 + l15) * DEC + kb * 32 + q * 8);
          #pragma unroll
          for (int m = 0; m < 4; ++m) acc[g][m] = mfma(a[m], bb, acc[g][m]);
        }
      }
      // epilogue: gates -> h_next written directly into nxt buffer
      int colh = wn * 64 + c * 16 + l15;
      f32x4 tabR = *(const f32x4*)(gt + (0 * 256 + colh) * 4);
      f32x4 tabZ = *(const f32x4*)(gt + (1 * 256 + colh) * 4);
      f32x4 tabN = *(const f32x4*)(gt + (2 * 256 + colh) * 4);
      #pragma unroll
      for (int mp = 0; mp < 2; ++mp) {
        u32x4 gvR = gi4[(c * 6 + mp * 3 + 0) * 64 + lane];
        u32x4 gvZ = gi4[(c * 6 + mp * 3 + 1) * 64 + lane];
        u32x4 gvN = gi4[(c * 6 + mp * 3 + 2) * 64 + lane];
        #pragma unroll
        for (int mh = 0; mh < 2; ++mh) {
          const int m = mp * 2 + mh;
          int row0 = wm * 64 + m * 16 + q * 4;
          f32x4 muA = *(const f32x4*)(mul + row0 * 2);        // rows r=0,1
          f32x4 muB = *(const f32x4*)(mul + row0 * 2 + 4);    // rows r=2,3
          #pragma unroll
          for (int p = 0; p < 2; ++p) {
            float mx0 = p ? muB.x : muA.x, my0 = p ? muB.y : muA.y;
            float mx1 = p ? muB.z : muA.z, my1 = p ? muB.w : muA.w;
            u32 gR = gvR[mh * 2 + p], gZ = gvZ[mh * 2 + p], gN = gvN[mh * 2 + p];
            const int r0 = p * 2, r1 = p * 2 + 1;
            int rowa = row0 + p * 2;
            float hp0 = b2f(*(const u16*)(cur + rowa * H_STRIDE + colh * 2));
            float hp1 = b2f(*(const u16*)(cur + (rowa + 1) * H_STRIDE + colh * 2));
            float rin0 = acc[0][m][r0] + tabR.z + gilo(gR) + mx0 * tabR.x + my0 * tabR.y;
            float rin1 = acc[0][m][r1] + tabR.z + gihi(gR) + mx1 * tabR.x + my1 * tabR.y;
            float zin0 = acc[1][m][r0] + tabZ.z + gilo(gZ) + mx0 * tabZ.x + my0 * tabZ.y;
            float zin1 = acc[1][m][r1] + tabZ.z + gihi(gZ) + mx1 * tabZ.x + my1 * tabZ.y;
            float hn0 = acc[2][m][r0] + tabN.z;
            float hn1 = acc[2][m][r1] + tabN.z;
            float rr0 = sigm(rin0), rr1 = sigm(rin1);
            float zz0 = sigm(zin0), zz1 = sigm(zin1);
            float nin0 = gilo(gN) + mx0 * tabN.x + my0 * tabN.y + rr0 * hn0;
            float nin1 = gihi(gN) + mx1 * tabN.x + my1 * tabN.y + rr1 * hn1;
            float nn0 = tanh_(nin0), nn1 = tanh_(nin1);
            float hv0 = nn0 + zz0 * (hp0 - nn0);
            float hv1 = nn1 + zz1 * (hp1 - nn1);
            *(u16*)(nxt + rowa * H_STRIDE + colh * 2) = f2b(hv0);
            *(u16*)(nxt + (rowa + 1) * H_STRIDE + colh * 2) = f2b(hv1);
          }
        }
      }
    }
    __syncthreads();  // barrier 1: nxt fully written; cur reads done
    // mu/cov GEMV via MFMA on h_next (nxt): each wave owns 16 rows
    {
      f32x4 acc2 = (f32x4)(0.0f);
      #pragma unroll
      for (int kb = 0; kb < 8; ++kb) {
        s16x8 bb = {0, 0, 0, 0, 0, 0, 0, 0};
        if (l15 < 5) bb = *(const s16x8*)(woutb + l15 * 256 + kb * 32 + q * 8);
        s16x8 a = *(const s16x8*)(nxt + (w * 16 + l15) * H_STRIDE + kb * 64 + q * 16);
        acc2 = mfma(a, bb, acc2);
      }
      float bias = (l15 < 5) ? bo[l15] : 0.0f;
      #pragma unroll
      for (int r = 0; r < 4; ++r) {
        int row = w * 16 + q * 4 + r;
        long grow = rowg0 + row;
        float v = acc2[r] + bias;
        if (l15 == 0) { out[(grow * HORIZON + t) * 2] = v; mul[row * 2] = v; }
        else if (l15 == 1) { out[(grow * HORIZON + t) * 2 + 1] = v; mul[row * 2 + 1] = v; }
        else if (l15 == 2) { float cx = fminf(fmaxf(v, 0.2f), 1.0f); out[MU_N + (grow * HORIZON + t) * 4] = cx; }
        else if (l15 == 3) { float cc = fminf(fmaxf(v, -0.1f), 0.1f);
                             out[MU_N + (grow * HORIZON + t) * 4 + 1] = cc;
                             out[MU_N + (grow * HORIZON + t) * 4 + 2] = cc; }
        else if (l15 == 4) { float cy = fminf(fmaxf(v, 0.2f), 1.0f); out[MU_N + (grow * HORIZON + t) * 4 + 3] = cy; }
      }
    }
    __syncthreads();  // barrier 2: mu visible for next step; nxt reads done
  }
}

extern "C" void kernel_launch(void* const* d_in, const int* in_sizes, int n_in,
                              void* d_out, int out_size, void* d_ws, size_t ws_size,
                              hipStream_t stream) {
  const float* zh      = (const float*)d_in[0];
  const float* W_hinit = (const float*)d_in[1];
  const float* b_hinit = (const float*)d_in[2];
  const float* W_ih    = (const float*)d_in[3];
  const float* b_ih    = (const float*)d_in[4];
  const float* W_hh    = (const float*)d_in[5];
  const float* b_hh    = (const float*)d_in[6];
  const float* W_mu    = (const float*)d_in[7];
  const float* b_mu    = (const float*)d_in[8];
  const float* W_cov   = (const float*)d_in[9];
  const float* b_cov   = (const float*)d_in[10];
  float* out = (float*)d_out;
  char* ws = (char*)d_ws;
  u16* whh_b    = (u16*)(ws + WS_WHH);
  u16* wiha_b   = (u16*)(ws + WS_WIHA);
  u16* whinit_b = (u16*)(ws + WS_WHINIT);
  u16* gi       = (u16*)(ws + WS_GI);

  cvt_whh<<<768, 256, 0, stream>>>(W_hh, whh_b);
  cvt_wiha<<<768, 384, 0, stream>>>(W_ih, wiha_b);
  cvt_whinit<<<384, 256, 0, stream>>>(W_hinit, whinit_b);

  hipFuncSetAttribute(reinterpret_cast<const void*>(traj_main),
                      hipFuncAttributeMaxDynamicSharedMemorySize, LDS_TOTAL);
  traj_main<<<GRIDN, NTHR, LDS_TOTAL, stream>>>(
      zh, b_hinit, W_ih, b_ih, b_hh, W_mu, b_mu, W_cov, b_cov,
      whh_b, wiha_b, whinit_b, gi, out);
}